// Round 4
// baseline (141.857 us; speedup 1.0000x reference)
//
#include <hip/hip_runtime.h>
#include <hip/hip_cooperative_groups.h>
#include <hip/hip_bf16.h>

namespace cg = cooperative_groups;

// Problem constants (T=512, B=32, D=128, 9 table rows after clipping).
#define TBPAIRS 16384
#define DEMB    128
#define NR      9
#define CAP     16384              // per-bucket perm capacity (worst case)
#define GRID    512                // 2 blocks/CU -> all co-resident (coop launch)

#define BPACK_U4    (NR * 2048)          // 18432 uint4 = 288 KB
#define BPACK_BYTES (BPACK_U4 * 16)      // 294912

#define LSTRIDE 130                // LDS row stride in bf16 elems

using short8 = __attribute__((ext_vector_type(8))) short;
using f32x4  = __attribute__((ext_vector_type(4))) float;

// fp32 -> bf16 round-to-nearest-even
__device__ __forceinline__ unsigned short f2bf(float f) {
    unsigned u = __float_as_uint(f);
    u = u + 0x7FFFu + ((u >> 16) & 1u);
    return (unsigned short)(u >> 16);
}

// ---------------------------------------------------------------------------
// Fused cooperative kernel.
// Phase A (blocks 0..63): bucketize -> perm + gcnt (atomic, gcnt pre-zeroed
//          by the tiny memset node). Blocks 64..99: pack table -> bpack
//          B-fragments via LDS (layout verified in prior rounds):
//          uint4 index r*2048 + nt*256 + ks*64 + lane holds
//          M[r][d = ks*32 + (lane>>4)*8 + j][e = nt*16 + (lane&15)], j=0..7
// grid.sync()
// Phase B (all 512 blocks): tile-indexed MFMA transfer (R4-proven loop).
// ---------------------------------------------------------------------------
__global__ __launch_bounds__(256) void fused_kernel(
    const int*   __restrict__ positions,
    const float* __restrict__ table,
    const float* __restrict__ x,
    uint4* __restrict__ bpack,
    int*   __restrict__ gcnt,
    int*   __restrict__ perm,
    float* __restrict__ out) {

    const int bid = blockIdx.x;
    const int tid = threadIdx.x;

    __shared__ unsigned short sm[32 * LSTRIDE];  // pack staging (phase A only)
    __shared__ int lcnt[NR];
    __shared__ int lbase[NR];
    __shared__ int cs[NR];
    __shared__ int tp[NR + 1];

    // ---------------- Phase A ----------------
    if (bid < 64) {
        if (tid < NR) lcnt[tid] = 0;
        __syncthreads();
        const int pair = bid * 256 + tid;
        const int p = positions[pair];
        const int r = (p < 8) ? p : 8;
        const int rank = atomicAdd(&lcnt[r], 1);
        __syncthreads();
        if (tid < NR) lbase[tid] = atomicAdd(&gcnt[tid], lcnt[tid]);
        __syncthreads();
        perm[r * CAP + lbase[r] + rank] = pair;
    } else if (bid < 100) {
        // pack: block = (r, ks); stage rows d = ks*32 + [0,32) in LDS
        const int pid = bid - 64;      // 0..35
        const int r   = pid >> 2;
        const int ks  = pid & 3;
        const float* M = table + (r * DEMB + ks * 32) * DEMB;

        // coalesced load: 32 rows x 128 floats = 1024 float4, 4 per thread
#pragma unroll
        for (int f4 = 0; f4 < 4; ++f4) {
            const int id   = f4 * 256 + tid;   // 0..1023
            const int row  = id >> 5;          // 0..31
            const int col4 = id & 31;          // float4 within row
            const float4 v = ((const float4*)(M + row * DEMB))[col4];
            unsigned short* dst = &sm[row * LSTRIDE + col4 * 4];
            dst[0] = f2bf(v.x); dst[1] = f2bf(v.y);
            dst[2] = f2bf(v.z); dst[3] = f2bf(v.w);
        }
        __syncthreads();

        // fragment assembly: 512 uint4 per block, 2 per thread
#pragma unroll
        for (int f = 0; f < 2; ++f) {
            const int fid  = f * 256 + tid;    // 0..511
            const int nt   = fid >> 6;         // 0..7
            const int lane = fid & 63;
            const int e    = nt * 16 + (lane & 15);
            const int ld0  = (lane >> 4) * 8;  // local d base
            union { unsigned short us[8]; uint4 v; } u;
#pragma unroll
            for (int j = 0; j < 8; ++j)
                u.us[j] = sm[(ld0 + j) * LSTRIDE + e];
            bpack[r * 2048 + nt * 256 + ks * 64 + lane] = u.v;
        }
    }

    // ---------------- grid-wide barrier ----------------
    cg::this_grid().sync();

    // ---------------- Phase B: transfer ----------------
    if (tid < NR) cs[tid] = gcnt[tid];
    __syncthreads();
    if (tid == 0) {
        int acc = 0;
#pragma unroll
        for (int r = 0; r < NR; ++r) { tp[r] = acc; acc += (cs[r] + 15) >> 4; }
        tp[NR] = acc;
    }
    __syncthreads();

    const int wave  = tid >> 6;
    const int lane  = tid & 63;
    const int m16   = lane & 15;   // m (pair-in-tile) for A; n (col) for C/D
    const int quad  = lane >> 4;
    const int total = tp[NR];

    for (int T = blockIdx.x * 4 + wave; T < total; T += GRID * 4) {
        int r = 0;
#pragma unroll
        for (int rr = 1; rr < NR; ++rr) r = (T >= tp[rr]) ? rr : r;
        const int tb = (T - tp[r]) * 16;
        const int c  = cs[r];
        const int nm = c - tb;            // valid pairs in tile (1..16)
        const int* pr = perm + r * CAP + tb;

        // ---- A fragments: A[m = lane&15][k = ks*32 + quad*8 + j]
        const int slotA = pr[(m16 < nm) ? m16 : 0];
        const float* xrow = x + (size_t)slotA * DEMB;
        short8 a[4];
#pragma unroll
        for (int ks = 0; ks < 4; ++ks) {
            const float4* s4 = (const float4*)(xrow + ks * 32 + quad * 8);
            const float4 f0 = s4[0];
            const float4 f1 = s4[1];
            union { unsigned short us[8]; short8 s8; } ua;
            ua.us[0] = f2bf(f0.x); ua.us[1] = f2bf(f0.y);
            ua.us[2] = f2bf(f0.z); ua.us[3] = f2bf(f0.w);
            ua.us[4] = f2bf(f1.x); ua.us[5] = f2bf(f1.y);
            ua.us[6] = f2bf(f1.z); ua.us[7] = f2bf(f1.w);
            a[ks] = ua.s8;
        }

        // ---- C/D rows: col = lane&15, row m = quad*4 + i
        int  prow[4];
        bool pval[4];
#pragma unroll
        for (int i = 0; i < 4; ++i) {
            const int m = quad * 4 + i;
            pval[i] = m < nm;
            prow[i] = pval[i] ? pr[m] : 0;
        }

        const uint4* bp = bpack + r * 2048 + lane;
#pragma unroll 2
        for (int nt = 0; nt < 8; ++nt) {
            f32x4 acc = {0.f, 0.f, 0.f, 0.f};
#pragma unroll
            for (int ks = 0; ks < 4; ++ks) {
                union { uint4 v4; short8 s8; } ub;
                ub.v4 = bp[(nt * 4 + ks) * 64];
                acc = __builtin_amdgcn_mfma_f32_16x16x32_bf16(a[ks], ub.s8, acc, 0, 0, 0);
            }
            const int col = nt * 16 + m16;
#pragma unroll
            for (int i = 0; i < 4; ++i)
                if (pval[i])
                    __builtin_nontemporal_store(acc[i], &out[(size_t)prow[i] * DEMB + col]);
        }
    }
}

extern "C" void kernel_launch(void* const* d_in, const int* in_sizes, int n_in,
                              void* d_out, int out_size, void* d_ws, size_t ws_size,
                              hipStream_t stream) {
    const int*   positions = (const int*)d_in[0];   // (16384,) int32
    const float* outputs   = (const float*)d_in[1]; // (16384, 128) fp32
    const float* table     = (const float*)d_in[2]; // (9, 128, 128) fp32
    float* out = (float*)d_out;                     // (16384, 128) fp32

    uint4* bpack = (uint4*)d_ws;                            // 288 KB
    int*   gcnt  = (int*)((char*)d_ws + BPACK_BYTES);       // 9 ints (pad 64 B)
    int*   perm  = (int*)((char*)d_ws + BPACK_BYTES + 64);  // 9*16384 ints

    hipMemsetAsync((void*)gcnt, 0, 64, stream);

    void* args[] = {(void*)&positions, (void*)&table, (void*)&outputs,
                    (void*)&bpack, (void*)&gcnt, (void*)&perm, (void*)&out};
    hipLaunchCooperativeKernel((const void*)fused_kernel, dim3(GRID), dim3(256),
                               args, 0, stream);
}

// Round 5
// 76.057 us; speedup vs baseline: 1.8652x; 1.8652x over previous
//
#include <hip/hip_runtime.h>

// Problem constants (T=512, B=32, D=128, 9 table rows after clipping).
#define TBPAIRS 16384
#define DEMB    128
#define NR      9
#define CAP     16384              // per-bucket perm region (64 blocks * 256 slots)
#define GRID2   512                // 2 blocks/CU for transfer

#define BPACK_U4    (NR * 2048)          // 18432 uint4 = 288 KB
#define BPACK_BYTES (BPACK_U4 * 16)      // 294912
#define CNTS_BYTES  (64 * 16 * 4)        // 64 blocks x 16 (padded from 9) ints = 4 KB

#define LSTRIDE 130                // LDS row stride in bf16 elems

using short8 = __attribute__((ext_vector_type(8))) short;
using f32x4  = __attribute__((ext_vector_type(4))) float;

// fp32 -> bf16 round-to-nearest-even
__device__ __forceinline__ unsigned short f2bf(float f) {
    unsigned u = __float_as_uint(f);
    u = u + 0x7FFFu + ((u >> 16) & 1u);
    return (unsigned short)(u >> 16);
}

// ---------------------------------------------------------------------------
// Kernel 1 — NO global atomics, NO memset dependency.
// blocks 0..63: bucketize 256 pairs each; write pairs to fixed per-block
//   perm slots perm[r*CAP + bid*256 + rank] (holes OK, never read) and
//   plain-store per-block counts cnts[bid*16 + r].
// blocks 64..99: pack table -> bpack B-fragments via LDS (proven layout):
//   uint4 index r*2048 + nt*256 + ks*64 + lane holds
//   M[r][d = ks*32 + (lane>>4)*8 + j][e = nt*16 + (lane&15)], j=0..7
// ---------------------------------------------------------------------------
__global__ __launch_bounds__(256) void prep_kernel(
    const int*   __restrict__ positions,
    const float* __restrict__ table,
    uint4* __restrict__ bpack,
    int*   __restrict__ cnts,
    int*   __restrict__ perm) {

    const int bid = blockIdx.x;
    const int tid = threadIdx.x;

    if (bid < 64) {
        __shared__ int lcnt[NR];
        if (tid < NR) lcnt[tid] = 0;
        __syncthreads();
        const int pair = bid * 256 + tid;
        const int p = positions[pair];
        const int r = (p < 8) ? p : 8;
        const int rank = atomicAdd(&lcnt[r], 1);   // LDS atomic only
        perm[r * CAP + bid * 256 + rank] = pair;
        __syncthreads();
        if (tid < NR) cnts[bid * 16 + tid] = lcnt[tid];
    } else {
        // ---- pack: block = (r, ks); stage rows d = ks*32 + [0,32) in LDS
        __shared__ unsigned short sm[32 * LSTRIDE];
        const int pid = bid - 64;      // 0..35
        const int r   = pid >> 2;
        const int ks  = pid & 3;
        const float* M = table + (r * DEMB + ks * 32) * DEMB;  // rows ld=0..31

        // coalesced load: 32 rows x 128 floats = 1024 float4, 4 per thread
#pragma unroll
        for (int f4 = 0; f4 < 4; ++f4) {
            const int id   = f4 * 256 + tid;   // 0..1023
            const int row  = id >> 5;          // 0..31
            const int col4 = id & 31;          // float4 within row
            const float4 v = ((const float4*)(M + row * DEMB))[col4];
            unsigned short* dst = &sm[row * LSTRIDE + col4 * 4];
            dst[0] = f2bf(v.x); dst[1] = f2bf(v.y);
            dst[2] = f2bf(v.z); dst[3] = f2bf(v.w);
        }
        __syncthreads();

        // fragment assembly: 512 uint4 per block, 2 per thread
#pragma unroll
        for (int f = 0; f < 2; ++f) {
            const int fid  = f * 256 + tid;    // 0..511
            const int nt   = fid >> 6;         // 0..7
            const int lane = fid & 63;
            const int e    = nt * 16 + (lane & 15);
            const int ld0  = (lane >> 4) * 8;  // local d base
            union { unsigned short us[8]; uint4 v; } u;
#pragma unroll
            for (int j = 0; j < 8; ++j)
                u.us[j] = sm[(ld0 + j) * LSTRIDE + e];
            bpack[r * 2048 + nt * 256 + ks * 64 + lane] = u.v;
        }
    }
}

// ---------------------------------------------------------------------------
// Kernel 2: prologue builds per-bucket per-segment prefix sums in LDS from
// cnts (4 KB), then the proven MFMA tile loop; pair slots resolved by a
// 6-step binary search over 64 segment prefixes (LDS) + one perm load.
// C-row slots come from __shfl of the A-side lookup.
// ---------------------------------------------------------------------------
__global__ __launch_bounds__(256) void transfer_kernel(
    const float* __restrict__ x,
    const uint4* __restrict__ bpack,
    const int*   __restrict__ cnts,
    const int*   __restrict__ perm,
    float*       __restrict__ out) {

    __shared__ int scnt[64 * 16];
    __shared__ int pfx[NR][65];
    __shared__ int cs[NR];
    __shared__ int tp[NR + 1];

    const int tid = threadIdx.x;

    // stage counts: 1024 ints = 256 int4, one per thread
    ((int4*)scnt)[tid] = ((const int4*)cnts)[tid];
    __syncthreads();

    if (tid < NR) {
        int acc = 0;
#pragma unroll
        for (int b = 0; b < 64; ++b) { pfx[tid][b] = acc; acc += scnt[b * 16 + tid]; }
        pfx[tid][64] = acc;
        cs[tid] = acc;
    }
    __syncthreads();
    if (tid == 0) {
        int acc = 0;
#pragma unroll
        for (int r = 0; r < NR; ++r) { tp[r] = acc; acc += (cs[r] + 15) >> 4; }
        tp[NR] = acc;
    }
    __syncthreads();

    const int wave  = tid >> 6;
    const int lane  = tid & 63;
    const int m16   = lane & 15;   // m (pair-in-tile) for A; n (col) for C/D
    const int quad  = lane >> 4;
    const int total = tp[NR];

    for (int T = blockIdx.x * 4 + wave; T < total; T += GRID2 * 4) {
        int r = 0;
#pragma unroll
        for (int rr = 1; rr < NR; ++rr) r = (T >= tp[rr]) ? rr : r;
        const int tb = (T - tp[r]) * 16;
        const int nm = cs[r] - tb;        // valid pairs in tile (1..16 for last)

        // ---- resolve this lane's pair slot: global rank -> (segment, local)
        const int g = tb + ((m16 < nm) ? m16 : 0);
        int lo = 0, hi = 64;
#pragma unroll
        for (int it = 0; it < 6; ++it) {
            const int mid = (lo + hi) >> 1;
            const bool le = (pfx[r][mid] <= g);
            lo = le ? mid : lo;
            hi = le ? hi : mid;
        }
        const int slotA = perm[r * CAP + lo * 256 + (g - pfx[r][lo])];

        // ---- A fragments: A[m = lane&15][k = ks*32 + quad*8 + j]
        const float* xrow = x + (size_t)slotA * DEMB;
        short8 a[4];
#pragma unroll
        for (int ks = 0; ks < 4; ++ks) {
            const float4* s4 = (const float4*)(xrow + ks * 32 + quad * 8);
            const float4 f0 = s4[0];
            const float4 f1 = s4[1];
            union { unsigned short us[8]; short8 s8; } ua;
            ua.us[0] = f2bf(f0.x); ua.us[1] = f2bf(f0.y);
            ua.us[2] = f2bf(f0.z); ua.us[3] = f2bf(f0.w);
            ua.us[4] = f2bf(f1.x); ua.us[5] = f2bf(f1.y);
            ua.us[6] = f2bf(f1.z); ua.us[7] = f2bf(f1.w);
            a[ks] = ua.s8;
        }

        // ---- C/D rows: col = lane&15, row m = quad*4 + i; slots via shfl
        int  prow[4];
        bool pval[4];
#pragma unroll
        for (int i = 0; i < 4; ++i) {
            const int m = quad * 4 + i;
            pval[i] = m < nm;
            prow[i] = __shfl(slotA, (lane & 48) | m, 64);
        }

        const uint4* bp = bpack + r * 2048 + lane;
#pragma unroll 2
        for (int nt = 0; nt < 8; ++nt) {
            f32x4 acc = {0.f, 0.f, 0.f, 0.f};
#pragma unroll
            for (int ks = 0; ks < 4; ++ks) {
                union { uint4 v4; short8 s8; } ub;
                ub.v4 = bp[(nt * 4 + ks) * 64];
                acc = __builtin_amdgcn_mfma_f32_16x16x32_bf16(a[ks], ub.s8, acc, 0, 0, 0);
            }
            const int col = nt * 16 + m16;
#pragma unroll
            for (int i = 0; i < 4; ++i)
                if (pval[i])
                    out[(size_t)prow[i] * DEMB + col] = acc[i];
        }
    }
}

extern "C" void kernel_launch(void* const* d_in, const int* in_sizes, int n_in,
                              void* d_out, int out_size, void* d_ws, size_t ws_size,
                              hipStream_t stream) {
    const int*   positions = (const int*)d_in[0];   // (16384,) int32
    const float* outputs   = (const float*)d_in[1]; // (16384, 128) fp32
    const float* table     = (const float*)d_in[2]; // (9, 128, 128) fp32
    float* out = (float*)d_out;                     // (16384, 128) fp32

    uint4* bpack = (uint4*)d_ws;                                   // 288 KB
    int*   cnts  = (int*)((char*)d_ws + BPACK_BYTES);              // 4 KB
    int*   perm  = (int*)((char*)d_ws + BPACK_BYTES + CNTS_BYTES); // 9*16384 ints

    hipLaunchKernelGGL(prep_kernel, dim3(100), dim3(256), 0, stream,
                       positions, table, bpack, cnts, perm);
    hipLaunchKernelGGL(transfer_kernel, dim3(GRID2), dim3(256), 0, stream,
                       outputs, bpack, cnts, perm, out);
}

// Round 6
// 71.847 us; speedup vs baseline: 1.9744x; 1.0586x over previous
//
#include <hip/hip_runtime.h>

// T=512, B=32 -> 16384 (t,b) pairs, D=128, 9 effective table rows.
// positions uniform 0..15 -> bucket 8 (p>=8) holds ~50% of pairs.
//
// Single-dispatch design: block = (r, chunk). Each block
//   1) scans its positions slice, collects matching pair indices into LDS,
//   2) packs M[r] into LDS B-fragments (layout verified R1-R5),
//   3) runs 16x16x32 MFMA tiles with B from LDS, A gathered from x.
// No workspace, no global atomics, no cross-block dependencies.
#define DEMB    128
#define LSTRIDE 130                // LDS staging row stride (bank-conflict pad)

using short8 = __attribute__((ext_vector_type(8))) short;
using f32x4  = __attribute__((ext_vector_type(4))) float;

// fp32 -> bf16 round-to-nearest-even
__device__ __forceinline__ unsigned short f2bf(float f) {
    unsigned u = __float_as_uint(f);
    u = u + 0x7FFFu + ((u >> 16) & 1u);
    return (unsigned short)(u >> 16);
}

// B-fragment LDS layout (same index math as the proven global bpack):
//   frag[nt*256 + ks*64 + lane] (uint4) holds
//   M[r][d = ks*32 + (lane>>4)*8 + j][e = nt*16 + (lane&15)], j=0..7
__global__ __launch_bounds__(256) void mpt_kernel(
    const int*   __restrict__ positions,
    const float* __restrict__ table,
    const float* __restrict__ x,
    float*       __restrict__ out) {

    __shared__ unsigned short sm[32 * LSTRIDE];  // 8.3 KB pack staging
    __shared__ uint4 frag[2048];                 // 32 KB B-fragments for this r
    __shared__ int   sel[512];                   // matching pair indices
    __shared__ int   scnt;

    const int bid = blockIdx.x;
    const int tid = threadIdx.x;

    // ---- block -> (r, slice). r=8: 256 blocks x 64 pairs; r<8: 32 blocks x 512.
    int r, base, npos;
    if (bid < 256) { r = 8; base = bid * 64;  npos = 64;  }
    else { r = (bid - 256) >> 5; base = ((bid - 256) & 31) * 512; npos = 512; }

    if (tid == 0) scnt = 0;
    __syncthreads();

    // ---- 1) select matching pairs (order irrelevant: each pair's output row
    //         is computed independently; LDS-atomic rank only).
    for (int i = tid; i < npos; i += 256) {
        const int p = positions[base + i];
        const bool hit = (r == 8) ? (p >= 8) : (p == r);
        if (hit) { const int k = atomicAdd(&scnt, 1); sel[k] = base + i; }
    }

    // ---- 2) pack M[r] -> LDS B-fragments, quarter (ks) at a time.
    const float* Mr = table + r * DEMB * DEMB;
#pragma unroll
    for (int ks = 0; ks < 4; ++ks) {
        const float* M = Mr + ks * 32 * DEMB;   // rows ks*32 .. ks*32+31
        // stage 32 rows x 128 floats = 1024 float4, 4 per thread (coalesced)
#pragma unroll
        for (int f4 = 0; f4 < 4; ++f4) {
            const int id   = f4 * 256 + tid;    // 0..1023
            const int row  = id >> 5;           // 0..31
            const int col4 = id & 31;
            const float4 v = ((const float4*)(M + row * DEMB))[col4];
            unsigned short* dst = &sm[row * LSTRIDE + col4 * 4];
            dst[0] = f2bf(v.x); dst[1] = f2bf(v.y);
            dst[2] = f2bf(v.z); dst[3] = f2bf(v.w);
        }
        __syncthreads();
        // assemble 512 uint4 (2 per thread) for this ks quarter
#pragma unroll
        for (int f = 0; f < 2; ++f) {
            const int fid  = f * 256 + tid;     // 0..511
            const int nt   = fid >> 6;          // 0..7
            const int lane = fid & 63;
            const int e    = nt * 16 + (lane & 15);
            const int ld0  = (lane >> 4) * 8;
            union { unsigned short us[8]; uint4 v; } u;
#pragma unroll
            for (int j = 0; j < 8; ++j)
                u.us[j] = sm[(ld0 + j) * LSTRIDE + e];
            frag[nt * 256 + ks * 64 + lane] = u.v;
        }
        __syncthreads();   // also fences sel/scnt for phase 3 on last iter
    }

    // ---- 3) MFMA tiles over this block's pairs (proven core, B from LDS).
    const int wave = tid >> 6;
    const int lane = tid & 63;
    const int m16  = lane & 15;     // m (pair-in-tile) for A; n (col) for C/D
    const int quad = lane >> 4;
    const int cnt  = scnt;

    for (int tb = wave * 16; tb < cnt; tb += 64) {
        const int nm = ((cnt - tb) < 16) ? (cnt - tb) : 16;  // 1..16

        // A fragments: A[m = lane&15][k = ks*32 + quad*8 + j]
        const int slotA = sel[tb + ((m16 < nm) ? m16 : 0)];
        const float* xrow = x + (size_t)slotA * DEMB;
        short8 a[4];
#pragma unroll
        for (int ks = 0; ks < 4; ++ks) {
            const float4* s4 = (const float4*)(xrow + ks * 32 + quad * 8);
            const float4 f0 = s4[0];
            const float4 f1 = s4[1];
            union { unsigned short us[8]; short8 s8; } ua;
            ua.us[0] = f2bf(f0.x); ua.us[1] = f2bf(f0.y);
            ua.us[2] = f2bf(f0.z); ua.us[3] = f2bf(f0.w);
            ua.us[4] = f2bf(f1.x); ua.us[5] = f2bf(f1.y);
            ua.us[6] = f2bf(f1.z); ua.us[7] = f2bf(f1.w);
            a[ks] = ua.s8;
        }

        // C/D rows: col = lane&15, row m = quad*4 + i (slots straight from LDS)
        int  prow[4];
        bool pval[4];
#pragma unroll
        for (int i = 0; i < 4; ++i) {
            const int m = quad * 4 + i;
            pval[i] = m < nm;
            prow[i] = sel[tb + (pval[i] ? m : 0)];
        }

#pragma unroll 2
        for (int nt = 0; nt < 8; ++nt) {
            f32x4 acc = {0.f, 0.f, 0.f, 0.f};
#pragma unroll
            for (int ks = 0; ks < 4; ++ks) {
                union { uint4 v4; short8 s8; } ub;
                ub.v4 = frag[(nt * 4 + ks) * 64 + lane];
                acc = __builtin_amdgcn_mfma_f32_16x16x32_bf16(a[ks], ub.s8, acc, 0, 0, 0);
            }
            const int col = nt * 16 + m16;
#pragma unroll
            for (int i = 0; i < 4; ++i)
                if (pval[i])
                    out[(size_t)prow[i] * DEMB + col] = acc[i];
        }
    }
}

extern "C" void kernel_launch(void* const* d_in, const int* in_sizes, int n_in,
                              void* d_out, int out_size, void* d_ws, size_t ws_size,
                              hipStream_t stream) {
    const int*   positions = (const int*)d_in[0];   // (16384,) int32
    const float* outputs   = (const float*)d_in[1]; // (16384, 128) fp32
    const float* table     = (const float*)d_in[2]; // (9, 128, 128) fp32
    float* out = (float*)d_out;                     // (16384, 128) fp32

    hipLaunchKernelGGL(mpt_kernel, dim3(512), dim3(256), 0, stream,
                       positions, table, outputs, out);
}

// Round 8
// 70.424 us; speedup vs baseline: 2.0143x; 1.0202x over previous
//
#include <hip/hip_runtime.h>

// T=512, B=32 -> 16384 (t,b) pairs, D=128, 9 effective table rows.
// positions uniform 0..15 -> bucket 8 (p>=8) holds ~50% of pairs.
//
// Single-dispatch, single-pass-pack design: block = (r, chunk). Each block
//   1) issues ALL 16 table-staging loads (deep MLP), selects matching pairs
//      into LDS under the load shadow (LDS atomic, ~1 op/cyc),
//   2) stages full 128x128 M[r] -> bf16 LDS (1 barrier), assembles all 2048
//      B-fragments (1 barrier)  [layout verified R1-R6],
//   3) runs 16x16x32 MFMA tiles with B from LDS, A gathered from x.
// No workspace, no global atomics, 3 barriers total per block.
#define DEMB    128
#define LSTRIDE 130                // LDS staging row stride (bank-conflict pad)

using short8 = __attribute__((ext_vector_type(8))) short;
using f32x4  = __attribute__((ext_vector_type(4))) float;

// fp32 -> bf16 round-to-nearest-even
__device__ __forceinline__ unsigned short f2bf(float f) {
    unsigned u = __float_as_uint(f);
    u = u + 0x7FFFu + ((u >> 16) & 1u);
    return (unsigned short)(u >> 16);
}
__device__ __forceinline__ unsigned pack2(float a, float b) {
    return (unsigned)f2bf(a) | ((unsigned)f2bf(b) << 16);
}

// B-fragment LDS layout (same index math as the proven global bpack):
//   frag[nt*256 + ks*64 + lane] (uint4) holds
//   M[r][d = ks*32 + (lane>>4)*8 + j][e = nt*16 + (lane&15)], j=0..7
__global__ __launch_bounds__(256) void mpt_kernel(
    const int*   __restrict__ positions,
    const float* __restrict__ table,
    const float* __restrict__ x,
    float*       __restrict__ out) {

    __shared__ unsigned short sm[128 * LSTRIDE];  // 33.3 KB full-table staging
    __shared__ uint4 frag[2048];                  // 32 KB B-fragments for this r
    __shared__ int   sel[512];                    // matching pair indices
    __shared__ int   scnt;

    const int bid = blockIdx.x;
    const int tid = threadIdx.x;

    // ---- block -> (r, slice). r=8: 256 blocks x 64 pairs; r<8: 32 blocks x 512.
    int r, base, npos;
    if (bid < 256) { r = 8; base = bid * 64;  npos = 64;  }
    else { r = (bid - 256) >> 5; base = ((bid - 256) & 31) * 512; npos = 512; }

    if (tid == 0) scnt = 0;
    __syncthreads();          // fence scnt before atomics (placed BEFORE loads
                              // so the barrier's vmcnt drain costs nothing)

    // ---- 1) issue ALL table staging loads: 128 rows x 32 float4, 16/thread
    const float* Mr = table + r * DEMB * DEMB;
    float4 st[16];
#pragma unroll
    for (int f4 = 0; f4 < 16; ++f4) {
        const int id  = f4 * 256 + tid;     // 0..4095
        const int row = id >> 5;            // 0..127
        const int c4  = id & 31;            // float4 within row
        st[f4] = ((const float4*)(Mr + row * DEMB))[c4];
    }

    // ---- selection runs under the staging-load shadow (LDS atomic rank only)
    for (int i = tid; i < npos; i += 256) {
        const int p = positions[base + i];
        const bool hit = (r == 8) ? (p >= 8) : (p == r);
        if (hit) { const int k = atomicAdd(&scnt, 1); sel[k] = base + i; }
    }

    // ---- 2a) convert + store staging rows (packed dword writes, 2/float4)
#pragma unroll
    for (int f4 = 0; f4 < 16; ++f4) {
        const int id  = f4 * 256 + tid;
        const int row = id >> 5;
        const int c4  = id & 31;
        unsigned* dst = (unsigned*)&sm[row * LSTRIDE + c4 * 4];
        dst[0] = pack2(st[f4].x, st[f4].y);
        dst[1] = pack2(st[f4].z, st[f4].w);
    }
    __syncthreads();

    // ---- 2b) assemble all 2048 B-fragments, 8 per thread
#pragma unroll
    for (int f = 0; f < 8; ++f) {
        const int fid  = f * 256 + tid;     // 0..2047 = nt*256 + ks*64 + lane
        const int lane = fid & 63;
        const int ks   = (fid >> 6) & 3;
        const int nt   = fid >> 8;
        const int e    = nt * 16 + (lane & 15);
        const int d0   = ks * 32 + ((lane >> 4) << 3);
        union { unsigned short us[8]; uint4 v; } u;
#pragma unroll
        for (int j = 0; j < 8; ++j)
            u.us[j] = sm[(d0 + j) * LSTRIDE + e];
        frag[fid] = u.v;
    }
    __syncthreads();   // also fences sel/scnt for phase 3

    // ---- 3) MFMA tiles over this block's pairs (proven core, B from LDS).
    const int wave = tid >> 6;
    const int lane = tid & 63;
    const int m16  = lane & 15;     // m (pair-in-tile) for A; n (col) for C/D
    const int quad = lane >> 4;
    const int cnt  = scnt;

    for (int tb = wave * 16; tb < cnt; tb += 64) {
        const int nm = ((cnt - tb) < 16) ? (cnt - tb) : 16;  // 1..16

        // A fragments: A[m = lane&15][k = ks*32 + quad*8 + j]
        const int slotA = sel[tb + ((m16 < nm) ? m16 : 0)];
        const float* xrow = x + (size_t)slotA * DEMB;
        short8 a[4];
#pragma unroll
        for (int ks = 0; ks < 4; ++ks) {
            const float4* s4 = (const float4*)(xrow + ks * 32 + quad * 8);
            const float4 f0 = s4[0];
            const float4 f1 = s4[1];
            union { unsigned short us[8]; short8 s8; } ua;
            ua.us[0] = f2bf(f0.x); ua.us[1] = f2bf(f0.y);
            ua.us[2] = f2bf(f0.z); ua.us[3] = f2bf(f0.w);
            ua.us[4] = f2bf(f1.x); ua.us[5] = f2bf(f1.y);
            ua.us[6] = f2bf(f1.z); ua.us[7] = f2bf(f1.w);
            a[ks] = ua.s8;
        }

        // C/D rows: col = lane&15, row m = quad*4 + i (slots straight from LDS)
        int  prow[4];
        bool pval[4];
#pragma unroll
        for (int i = 0; i < 4; ++i) {
            const int m = quad * 4 + i;
            pval[i] = m < nm;
            prow[i] = sel[tb + (pval[i] ? m : 0)];
        }

#pragma unroll 2
        for (int nt = 0; nt < 8; ++nt) {
            f32x4 acc = {0.f, 0.f, 0.f, 0.f};
#pragma unroll
            for (int ks = 0; ks < 4; ++ks) {
                union { uint4 v4; short8 s8; } ub;
                ub.v4 = frag[(nt * 4 + ks) * 64 + lane];
                acc = __builtin_amdgcn_mfma_f32_16x16x32_bf16(a[ks], ub.s8, acc, 0, 0, 0);
            }
            const int col = nt * 16 + m16;
#pragma unroll
            for (int i = 0; i < 4; ++i)
                if (pval[i])
                    out[(size_t)prow[i] * DEMB + col] = acc[i];
        }
    }
}

extern "C" void kernel_launch(void* const* d_in, const int* in_sizes, int n_in,
                              void* d_out, int out_size, void* d_ws, size_t ws_size,
                              hipStream_t stream) {
    const int*   positions = (const int*)d_in[0];   // (16384,) int32
    const float* outputs   = (const float*)d_in[1]; // (16384, 128) fp32
    const float* table     = (const float*)d_in[2]; // (9, 128, 128) fp32
    float* out = (float*)d_out;                     // (16384, 128) fp32

    hipLaunchKernelGGL(mpt_kernel, dim3(512), dim3(256), 0, stream,
                       positions, table, outputs, out);
}